// Round 17
// baseline (90.584 us; speedup 1.0000x reference)
//
#include <hip/hip_runtime.h>
#include <hip/hip_bf16.h>

typedef __bf16 bf16x8 __attribute__((ext_vector_type(8)));
typedef float f32x4 __attribute__((ext_vector_type(4)));

#define NB 32
#define CIN 512
#define COUT 128
#define NP 3136   // 56*56
#define WIMG 56

__device__ __forceinline__ unsigned fenc(float f) {
    unsigned u = __float_as_uint(f);
    return (u & 0x80000000u) ? ~u : (u | 0x80000000u);
}
__device__ __forceinline__ float fdec(unsigned e) {
    unsigned u = (e & 0x80000000u) ? (e ^ 0x80000000u) : ~e;
    return __uint_as_float(u);
}
__device__ __forceinline__ float bflo(unsigned u) { return __uint_as_float(u << 16); }
__device__ __forceinline__ float bfhi(unsigned u) { return __uint_as_float(u & 0xffff0000u); }

// two f32 -> two fp8 e4m3 bytes (HW cvt), returned in low 16 bits
__device__ __forceinline__ unsigned cvt2_fp8(float a, float b) {
    unsigned r;
    asm volatile("v_cvt_pk_fp8_f32 %0, %1, %2" : "=&v"(r) : "v"(a), "v"(b));
    return r & 0xffffu;
}
__device__ __forceinline__ unsigned pack4_fp8(unsigned u01, unsigned u23) {
    unsigned lo = cvt2_fp8(bflo(u01), bfhi(u01));
    unsigned hi = cvt2_fp8(bflo(u23), bfhi(u23));
    return lo | (hi << 16);
}
// fp8 e4m3 decode entry for byte v
__device__ __forceinline__ float fp8_entry(int v) {
    unsigned s = (v >> 7) & 1, e = (v >> 3) & 15, m = v & 7;
    if (e) return __uint_as_float((s << 31) | ((e + 120) << 23) | (m << 20));
    float f = (float)m * 0x1p-9f;
    return s ? -f : f;
}

// Relaxed barrier: LDS-visibility only, no vmcnt drain.
__device__ __forceinline__ void lds_barrier() {
    asm volatile("s_waitcnt lgkmcnt(0)" ::: "memory");
    __builtin_amdgcn_s_barrier();
    __builtin_amdgcn_sched_barrier(0);
}

// ---------------------------------------------------------------------------
// Kernel 0: W f32 -> bf16, plus zero-init of sumh/mxenc.
// ---------------------------------------------------------------------------
__global__ __launch_bounds__(256) void k_wcvt(const float* __restrict__ wp,
                                              ushort* __restrict__ wb,
                                              unsigned* __restrict__ zero8k)
{
    int i = blockIdx.x * 256 + threadIdx.x;
    if (i < 2 * NB * COUT) zero8k[i] = 0u;
    float4 f = *(const float4*)(wp + i * 4);
    ushort4 u;
    __bf16 b0 = (__bf16)f.x, b1 = (__bf16)f.y, b2 = (__bf16)f.z, b3 = (__bf16)f.w;
    u.x = *(ushort*)&b0; u.y = *(ushort*)&b1; u.z = *(ushort*)&b2; u.w = *(ushort*)&b3;
    *(ushort4*)(wb + i * 4) = u;
}

// ---------------------------------------------------------------------------
// Kernel 1: bf16 GEMM + BN + SiLU + h store (fp8) + per-(b,o) sum/max.
// R17: 32 waves/CU config. BM=128, BN=64, 1568 blocks, 512 threads, 8 waves
// 4Mx2N. X double-buffered (16KB), W SINGLE-buffered (16KB) -> 35KB LDS
// -> 4 blocks/CU; launch_bounds(512,8) caps VGPR at 64 (est. use ~55).
// Per kc: [bar] issue-prefetch + write X(kc+1) + compute(kc) [bar] write W(kc+1).
// ---------------------------------------------------------------------------
__global__ __launch_bounds__(512, 8) void k_main(
    const float* __restrict__ x, const ushort* __restrict__ wb,
    const float* __restrict__ bn_g, const float* __restrict__ bn_b,
    const float* __restrict__ bn_m, const float* __restrict__ bn_v,
    uchar* __restrict__ hout, float* __restrict__ sumh, unsigned* __restrict__ mxenc)
{
    __shared__ __align__(16) ushort Xs[2][64 * 64];   // 8KB each
    __shared__ __align__(16) ushort Ws[128 * 64];     // 16KB; epilogue h-tile
    __shared__ float bnss[256];
    __shared__ float redS[2][COUT];
    __shared__ float redM[2][COUT];

    const int bid  = blockIdx.x;                    // 0..1567, 1568 % 8 == 0
    const int swz  = (bid & 7) * 196 + (bid >> 3);  // bijective XCD swizzle
    const int t    = threadIdx.x;
    const int b    = swz / 49;
    const int p0   = (swz % 49) * 64;
    const int lane = t & 63;
    const int l15  = lane & 15;
    const int lg   = lane >> 4;     // 0..3
    const int w    = t >> 6;        // wave 0..7
    const int wm   = w >> 1;        // 0..3: o-base wm*32
    const int wn   = w & 1;         // 0..1: p-base wn*32

    if (t < COUT) {
        float sc = bn_g[t] * rsqrtf(bn_v[t] + 1e-5f);
        bnss[t]        = sc;
        bnss[t + COUT] = bn_b[t] - bn_m[t] * sc;
    }

    // ---- X staging: thread stages row p=t&63, k-octet kg=t>>6
    const int pr = t & 63;
    const int kg = t >> 6;
    const float* xb = x + ((size_t)b * CIN) * NP + p0 + pr;
    const int xbyte = pr * 128 + ((kg * 16) ^ ((pr & 7) << 4));

    // ---- W staging: thread t stages o=t>>2, 16 bf16 at k=(t&3)*16
    const int ow = t >> 2, kq = t & 3;
    const ushort* wsrc = wb + ow * CIN + kq * 16;
    const int wbyte0 = ow * 128 + ((kq * 32) ^ ((ow & 7) << 4));
    const int wbyte1 = ow * 128 + ((kq * 32 + 16) ^ ((ow & 7) << 4));

    f32x4 acc[2][2];
#pragma unroll
    for (int mf = 0; mf < 2; ++mf)
#pragma unroll
        for (int nf = 0; nf < 2; ++nf) acc[mf][nf] = (f32x4){0.f, 0.f, 0.f, 0.f};

    float ldx[2][8];    // dist-2 X prefetch
    uint4 ldw0, ldw1;   // dist-1 W prefetch (L2-hot)

    // ---- prologue: issue X tiles 0,1; W tile 0; write X0, W0
#pragma unroll
    for (int j = 0; j < 8; ++j) {
        ldx[0][j] = xb[(kg * 8 + j) * NP];
        ldx[1][j] = xb[(64 + kg * 8 + j) * NP];
    }
    ldw0 = *(const uint4*)(wsrc);
    ldw1 = *(const uint4*)(wsrc + 8);
    {
        bf16x8 v8;
#pragma unroll
        for (int j = 0; j < 8; ++j) v8[j] = (__bf16)ldx[0][j];
        *(bf16x8*)((char*)Xs[0] + xbyte) = v8;
        *(uint4*)((char*)Ws + wbyte0) = ldw0;
        *(uint4*)((char*)Ws + wbyte1) = ldw1;
    }

#pragma unroll
    for (int kc = 0; kc < 8; ++kc) {
        lds_barrier();      // X(kc) + W(kc) writes visible; compute(kc-1) done
        // issue X tile kc+2 (dist-2) into the slot freed by tile kc
        if (kc < 6) {
#pragma unroll
            for (int j = 0; j < 8; ++j)
                ldx[kc & 1][j] = xb[((kc + 2) * 64 + kg * 8 + j) * NP];
        }
        // issue W tile kc+1 (dist-1)
        if (kc < 7) {
            ldw0 = *(const uint4*)(wsrc + (kc + 1) * 64);
            ldw1 = *(const uint4*)(wsrc + (kc + 1) * 64 + 8);
        }
        // write X(kc+1) early — its buffer's readers finished at compute(kc-1)
        if (kc < 7) {
            bf16x8 v8;
#pragma unroll
            for (int j = 0; j < 8; ++j) v8[j] = (__bf16)ldx[(kc + 1) & 1][j];
            *(bf16x8*)((char*)Xs[(kc + 1) & 1] + xbyte) = v8;
        }
        // compute tile kc
#pragma unroll
        for (int ks = 0; ks < 2; ++ks) {
            bf16x8 af[2], bfr[2];
#pragma unroll
            for (int mf = 0; mf < 2; ++mf) {
                int o = wm * 32 + mf * 16 + l15;
                af[mf] = *(const bf16x8*)((const char*)Ws
                          + o * 128 + ((ks * 64 + lg * 16) ^ ((o & 7) << 4)));
            }
#pragma unroll
            for (int nf = 0; nf < 2; ++nf) {
                int p = wn * 32 + nf * 16 + l15;
                bfr[nf] = *(const bf16x8*)((const char*)Xs[kc & 1]
                           + p * 128 + ((ks * 64 + lg * 16) ^ ((p & 7) << 4)));
            }
#pragma unroll
            for (int mf = 0; mf < 2; ++mf)
#pragma unroll
                for (int nf = 0; nf < 2; ++nf)
                    acc[mf][nf] = __builtin_amdgcn_mfma_f32_16x16x32_bf16(
                        af[mf], bfr[nf], acc[mf][nf], 0, 0, 0);
        }
        lds_barrier();      // all waves' W-reads of tile kc complete
        // write W(kc+1) into the single buffer
        if (kc < 7) {
            *(uint4*)((char*)Ws + wbyte0) = ldw0;
            *(uint4*)((char*)Ws + wbyte1) = ldw1;
        }
    }

    // ---- epilogue: BN + SiLU, stage h (bf16) in LDS (over Ws), partials
    ushort* Hs = (ushort*)Ws;        // [128 o][64 p] ushort = 16KB
#pragma unroll
    for (int mf = 0; mf < 2; ++mf) {
#pragma unroll
        for (int reg = 0; reg < 4; ++reg) {
            int o = wm * 32 + mf * 16 + lg * 4 + reg;
            float sc = bnss[o], sh = bnss[o + COUT];
            float s_ = 0.f, m_ = -1e30f;
#pragma unroll
            for (int nf = 0; nf < 2; ++nf) {
                float d    = acc[mf][nf][reg];
                float hval = d * sc + sh;
                hval       = hval / (1.f + __expf(-hval));
                s_ += hval;
                m_ = fmaxf(m_, hval);
                __bf16 hb = (__bf16)hval;
                Hs[o * 64 + wn * 32 + nf * 16 + l15] = *(ushort*)&hb;
            }
#pragma unroll
            for (int d = 1; d < 16; d <<= 1) {
                s_ += __shfl_xor(s_, d, 64);
                m_ = fmaxf(m_, __shfl_xor(m_, d, 64));
            }
            if (l15 == 0) {
                redS[wn][o] = s_;
                redM[wn][o] = m_;
            }
        }
    }
    __syncthreads();
    if (t < COUT) {
        atomicAdd(&sumh[b * COUT + t], redS[0][t] + redS[1][t]);
        atomicMax(&mxenc[b * COUT + t], fenc(fmaxf(redM[0][t], redM[1][t])));
    }
    // coalesced fp8 h write: thread t -> row t>>2, 16 bytes at (t&3)*16
    {
        int orow = t >> 2, c = t & 3;
        uint4 a  = *(const uint4*)&Hs[orow * 64 + c * 16];
        uint4 b4 = *(const uint4*)&Hs[orow * 64 + c * 16 + 8];
        uint4 o4;
        o4.x = pack4_fp8(a.x, a.y);
        o4.y = pack4_fp8(a.z, a.w);
        o4.z = pack4_fp8(b4.x, b4.y);
        o4.w = pack4_fp8(b4.z, b4.w);
        *(uint4*)&hout[((size_t)b * COUT + orow) * NP + p0 + c * 16] = o4;
    }
}

// ---------------------------------------------------------------------------
// Kernel 2: spatial stats of (h * ca), h in fp8 (LDS decode table).
// Inline ca MLP; block x==0 publishes ca. sbuf[z][b][{sum,max}][p].
// ---------------------------------------------------------------------------
__global__ __launch_bounds__(256) void k_sstat(const uchar* __restrict__ h,
                                               const float* __restrict__ sumh,
                                               const unsigned* __restrict__ mxenc,
                                               const float* __restrict__ w1,
                                               const float* __restrict__ w2,
                                               float* __restrict__ ca,
                                               float* __restrict__ sbuf)
{
    int b = blockIdx.y, z = blockIdx.z;
    int t = threadIdx.x;
    __shared__ float avg[128], mx[128], r1[16], cas[32], tab[256];
    tab[t] = fp8_entry(t);
    if (t < 128) {
        avg[t] = sumh[b * COUT + t] * (1.f / (float)NP);
        mx[t]  = fdec(mxenc[b * COUT + t]);
    }
    __syncthreads();
    if (t < 16) {
        int r = t & 7;
        const float* p = (t < 8) ? avg : mx;
        float s = 0.f;
        for (int c = 0; c < 128; ++c) s += w1[r * 128 + c] * p[c];
        r1[t] = fmaxf(s, 0.f);
    }
    __syncthreads();
    if (t < 32) {
        int o = z * 32 + t;
        float s = 0.f;
#pragma unroll
        for (int r = 0; r < 8; ++r) s += w2[o * 8 + r] * (r1[r] + r1[r + 8]);
        float cv = 1.f / (1.f + __expf(-s));
        cas[t] = cv;
        if (blockIdx.x == 0) ca[b * COUT + o] = cv;
    }
    __syncthreads();

    int idx = blockIdx.x * 256 + t;   // quad index
    if (idx >= NP / 4) return;
    int p = idx * 4;
    const uchar* hb = h + ((size_t)(b * COUT + z * 32)) * NP + p;
    float s0 = 0.f, s1 = 0.f, s2 = 0.f, s3 = 0.f;
    float m0 = -1e30f, m1 = -1e30f, m2 = -1e30f, m3 = -1e30f;
#pragma unroll 4
    for (int c = 0; c < 32; ++c) {
        unsigned u = *(const unsigned*)(hb + (size_t)c * NP);
        float cv = cas[c];
        float v0 = tab[u & 255] * cv;
        float v1 = tab[(u >> 8) & 255] * cv;
        float v2 = tab[(u >> 16) & 255] * cv;
        float v3 = tab[u >> 24] * cv;
        s0 += v0; s1 += v1; s2 += v2; s3 += v3;
        m0 = fmaxf(m0, v0); m1 = fmaxf(m1, v1);
        m2 = fmaxf(m2, v2); m3 = fmaxf(m3, v3);
    }
    float* sb = sbuf + ((size_t)(z * NB + b) * 2) * NP;
    *(float4*)&sb[p]      = make_float4(s0, s1, s2, s3);
    *(float4*)&sb[NP + p] = make_float4(m0, m1, m2, m3);
}

// ---------------------------------------------------------------------------
// Kernel 3: combine quarters, 7x7 conv (pad 3) + sigmoid -> sigsa[32,3136]
// ---------------------------------------------------------------------------
__global__ __launch_bounds__(256) void k_conv(const float* __restrict__ sbuf,
                                              const float* __restrict__ saw,
                                              float* __restrict__ sigsa)
{
    int band = blockIdx.x, b = blockIdx.y;
    int y0 = band * 7;
    int t = threadIdx.x;
    __shared__ float s[2][13 * WIMG];
    __shared__ float w[98];
    if (t < 98) w[t] = saw[t];
    for (int i = t; i < 13 * WIMG; i += 256) {
        int yy = y0 - 3 + i / WIMG;
        float vs = 0.f, vm = 0.f;
        if (yy >= 0 && yy < WIMG) {
            int p = yy * WIMG + (i % WIMG);
            float ssum = 0.f, smax = -1e30f;
#pragma unroll
            for (int z = 0; z < 4; ++z) {
                const float* sb = sbuf + ((size_t)(z * NB + b) * 2) * NP;
                ssum += sb[p];
                smax = fmaxf(smax, sb[NP + p]);
            }
            vs = ssum * (1.f / (float)COUT);
            vm = smax;
        }
        s[0][i] = vs;
        s[1][i] = vm;
    }
    __syncthreads();
    for (int i = t; i < 7 * WIMG; i += 256) {
        int ly = i / WIMG, px = i % WIMG;
        float a = 0.f;
#pragma unroll
        for (int ch = 0; ch < 2; ++ch) {
#pragma unroll
            for (int dy = 0; dy < 7; ++dy) {
                int li = (ly + dy) * WIMG;
                for (int dx = 0; dx < 7; ++dx) {
                    int xx = px + dx - 3;
                    if (xx < 0 || xx >= WIMG) continue;
                    a += s[ch][li + xx] * w[ch * 49 + dy * 7 + dx];
                }
            }
        }
        sigsa[b * NP + (y0 + ly) * WIMG + px] = 1.f / (1.f + __expf(-a));
    }
}

// ---------------------------------------------------------------------------
// Kernel 4: t = sum_p h * sigsa ; y = (sum_h + ca*t)/P.  One block per (b,o).
// ---------------------------------------------------------------------------
__global__ __launch_bounds__(256) void k_wsum(const uchar* __restrict__ h,
                                              const float* __restrict__ sigsa,
                                              const float* __restrict__ sumh,
                                              const float* __restrict__ ca,
                                              float* __restrict__ y)
{
    int bo = blockIdx.x;          // b*128+o
    int b = bo >> 7;
    int t = threadIdx.x;
    __shared__ float tab[256];
    __shared__ float part[4];
    tab[t] = fp8_entry(t);
    __syncthreads();
    const uchar* hr = h + (size_t)bo * NP;
    const float* sg  = sigsa + (size_t)b * NP;
    float s = 0.f;
#pragma unroll
    for (int i = 0; i < 3; ++i) {
        int q = i * 256 + t;
        unsigned u = *(const unsigned*)(hr + q * 4);
        float4 g = *(const float4*)(sg + q * 4);
        s += tab[u & 255] * g.x + tab[(u >> 8) & 255] * g.y
           + tab[(u >> 16) & 255] * g.z + tab[u >> 24] * g.w;
    }
    if (t < 16) {
        int q = 768 + t;
        unsigned u = *(const unsigned*)(hr + q * 4);
        float4 g = *(const float4*)(sg + q * 4);
        s += tab[u & 255] * g.x + tab[(u >> 8) & 255] * g.y
           + tab[(u >> 16) & 255] * g.z + tab[u >> 24] * g.w;
    }
#pragma unroll
    for (int d = 1; d < 64; d <<= 1) s += __shfl_xor(s, d, 64);
    if ((t & 63) == 0) part[t >> 6] = s;
    __syncthreads();
    if (t == 0) {
        float tt = part[0] + part[1] + part[2] + part[3];
        y[bo] = (sumh[bo] + ca[bo] * tt) * (1.f / (float)NP);
    }
}

// ---------------------------------------------------------------------------
// Kernel 5: LayerNorm over channels -> out[32,128]
// ---------------------------------------------------------------------------
__global__ void k_ln(const float* __restrict__ y, const float* __restrict__ g,
                     const float* __restrict__ bta, float* __restrict__ out)
{
    int b = blockIdx.x, t = threadIdx.x;  // 128 threads
    __shared__ float pr[2], pr2[2];
    float v = y[b * COUT + t];
    float s = v;
#pragma unroll
    for (int d = 1; d < 64; d <<= 1) s += __shfl_xor(s, d, 64);
    if ((t & 63) == 0) pr[t >> 6] = s;
    __syncthreads();
    float mu = (pr[0] + pr[1]) * (1.f / (float)COUT);
    float dv = v - mu;
    float q = dv * dv;
#pragma unroll
    for (int d = 1; d < 64; d <<= 1) q += __shfl_xor(q, d, 64);
    if ((t & 63) == 0) pr2[t >> 6] = q;
    __syncthreads();
    float var = (pr2[0] + pr2[1]) * (1.f / (float)COUT);
    out[b * COUT + t] = dv * rsqrtf(var + 1e-5f) * g[t] + bta[t];
}

// ---------------------------------------------------------------------------
extern "C" void kernel_launch(void* const* d_in, const int* in_sizes, int n_in,
                              void* d_out, int out_size, void* d_ws, size_t ws_size,
                              hipStream_t stream)
{
    const float* x     = (const float*)d_in[0];
    const float* wp    = (const float*)d_in[1];
    const float* bn_g  = (const float*)d_in[2];
    const float* bn_b  = (const float*)d_in[3];
    const float* bn_m  = (const float*)d_in[4];
    const float* bn_v  = (const float*)d_in[5];
    const float* ca_w1 = (const float*)d_in[6];
    const float* ca_w2 = (const float*)d_in[7];
    const float* sa_w  = (const float*)d_in[8];
    const float* ln_g  = (const float*)d_in[9];
    const float* ln_b  = (const float*)d_in[10];
    float* out = (float*)d_out;

    char* ws = (char*)d_ws;
    size_t off = 0;
    uchar*    hbuf  = (uchar*)(ws + off);    off += (size_t)NB * COUT * NP;      // 12.8 MB
    float*    sumh  = (float*)(ws + off);    off += NB * COUT * 4;               // 16 KB
    unsigned* mxenc = (unsigned*)(ws + off); off += NB * COUT * 4;               // 16 KB
    float*    ca    = (float*)(ws + off);    off += NB * COUT * 4;               // 16 KB
    float*    sbuf  = (float*)(ws + off);    off += (size_t)4 * NB * 2 * NP * 4; // 3.2 MB
    float*    sigsa = (float*)(ws + off);    off += (size_t)NB * NP * 4;         // 0.4 MB
    float*    ybuf  = (float*)(ws + off);    off += NB * COUT * 4;
    ushort*   wb16  = (ushort*)(ws + off);   off += (size_t)COUT * CIN * 2;      // 128 KB

    k_wcvt<<<64, 256, 0, stream>>>(wp, wb16, (unsigned*)sumh);
    k_main<<<NB * 49, 512, 0, stream>>>(x, wb16, bn_g, bn_b, bn_m, bn_v, hbuf, sumh, mxenc);
    k_sstat<<<dim3(4, NB, 4), 256, 0, stream>>>(hbuf, sumh, mxenc, ca_w1, ca_w2, ca, sbuf);
    k_conv<<<dim3(8, NB), 256, 0, stream>>>(sbuf, sa_w, sigsa);
    k_wsum<<<NB * COUT, 256, 0, stream>>>(hbuf, sigsa, sumh, ca, ybuf);
    k_ln<<<NB, 128, 0, stream>>>(ybuf, ln_g, ln_b, out);
}

// Round 18
// 79.239 us; speedup vs baseline: 1.1432x; 1.1432x over previous
//
#include <hip/hip_runtime.h>
#include <hip/hip_bf16.h>

typedef __bf16 bf16x8 __attribute__((ext_vector_type(8)));
typedef float f32x4 __attribute__((ext_vector_type(4)));

#define NB 32
#define CIN 512
#define COUT 128
#define NP 3136   // 56*56
#define WIMG 56

__device__ __forceinline__ unsigned fenc(float f) {
    unsigned u = __float_as_uint(f);
    return (u & 0x80000000u) ? ~u : (u | 0x80000000u);
}
__device__ __forceinline__ float fdec(unsigned e) {
    unsigned u = (e & 0x80000000u) ? (e ^ 0x80000000u) : ~e;
    return __uint_as_float(u);
}
__device__ __forceinline__ float bflo(unsigned u) { return __uint_as_float(u << 16); }
__device__ __forceinline__ float bfhi(unsigned u) { return __uint_as_float(u & 0xffff0000u); }

// two f32 -> two fp8 e4m3 bytes (HW cvt), returned in low 16 bits
__device__ __forceinline__ unsigned cvt2_fp8(float a, float b) {
    unsigned r;
    asm volatile("v_cvt_pk_fp8_f32 %0, %1, %2" : "=&v"(r) : "v"(a), "v"(b));
    return r & 0xffffu;
}
__device__ __forceinline__ unsigned pack4_fp8(unsigned u01, unsigned u23) {
    unsigned lo = cvt2_fp8(bflo(u01), bfhi(u01));
    unsigned hi = cvt2_fp8(bflo(u23), bfhi(u23));
    return lo | (hi << 16);
}
// fp8 e4m3 decode entry for byte v
__device__ __forceinline__ float fp8_entry(int v) {
    unsigned s = (v >> 7) & 1, e = (v >> 3) & 15, m = v & 7;
    if (e) return __uint_as_float((s << 31) | ((e + 120) << 23) | (m << 20));
    float f = (float)m * 0x1p-9f;
    return s ? -f : f;
}

// Relaxed barrier: LDS-visibility only, no vmcnt drain.
__device__ __forceinline__ void lds_barrier() {
    asm volatile("s_waitcnt lgkmcnt(0)" ::: "memory");
    __builtin_amdgcn_s_barrier();
    __builtin_amdgcn_sched_barrier(0);
}

// ---------------------------------------------------------------------------
// Kernel 0: W f32 -> bf16, plus zero-init of sumh/mxenc.
// ---------------------------------------------------------------------------
__global__ __launch_bounds__(256) void k_wcvt(const float* __restrict__ wp,
                                              ushort* __restrict__ wb,
                                              unsigned* __restrict__ zero8k)
{
    int i = blockIdx.x * 256 + threadIdx.x;
    if (i < 2 * NB * COUT) zero8k[i] = 0u;
    float4 f = *(const float4*)(wp + i * 4);
    ushort4 u;
    __bf16 b0 = (__bf16)f.x, b1 = (__bf16)f.y, b2 = (__bf16)f.z, b3 = (__bf16)f.w;
    u.x = *(ushort*)&b0; u.y = *(ushort*)&b1; u.z = *(ushort*)&b2; u.w = *(ushort*)&b3;
    *(ushort4*)(wb + i * 4) = u;
}

// ---------------------------------------------------------------------------
// Kernel 1: bf16 GEMM + BN + SiLU + h store (fp8) + per-(b,o) sum/max.
// BM=128, BN=64, 1568 blocks, 512 threads, 8 waves as 4M x 2N (mf=2, nf=2).
// W & X in LDS dbuf (48KB -> 3 blocks/CU = 24 waves/CU). Cross-wave LDS
// combine -> 128 atomic pairs per block. h written as fp8. (session best)
// ---------------------------------------------------------------------------
__global__ __launch_bounds__(512, 6) void k_main(
    const float* __restrict__ x, const ushort* __restrict__ wb,
    const float* __restrict__ bn_g, const float* __restrict__ bn_b,
    const float* __restrict__ bn_m, const float* __restrict__ bn_v,
    uchar* __restrict__ hout, float* __restrict__ sumh, unsigned* __restrict__ mxenc)
{
    __shared__ __align__(16) ushort Xs[2][64 * 64];   // 8KB each; epilogue h-tile
    __shared__ __align__(16) ushort Ws[2][128 * 64];  // 16KB each
    __shared__ float bnss[256];
    __shared__ float redS[2][COUT];
    __shared__ float redM[2][COUT];

    const int bid  = blockIdx.x;                    // 0..1567, 1568 % 8 == 0
    const int swz  = (bid & 7) * 196 + (bid >> 3);  // bijective XCD swizzle
    const int t    = threadIdx.x;
    const int b    = swz / 49;
    const int p0   = (swz % 49) * 64;
    const int lane = t & 63;
    const int l15  = lane & 15;
    const int lg   = lane >> 4;     // 0..3
    const int w    = t >> 6;        // wave 0..7
    const int wm   = w >> 1;        // 0..3: o-base wm*32
    const int wn   = w & 1;         // 0..1: p-base wn*32

    if (t < COUT) {
        float sc = bn_g[t] * rsqrtf(bn_v[t] + 1e-5f);
        bnss[t]        = sc;
        bnss[t + COUT] = bn_b[t] - bn_m[t] * sc;
    }

    // ---- X staging: thread stages row p=t&63, k-octet kg=t>>6
    const int pr = t & 63;
    const int kg = t >> 6;
    const float* xb = x + ((size_t)b * CIN) * NP + p0 + pr;
    const int xbyte = pr * 128 + ((kg * 16) ^ ((pr & 7) << 4));

    // ---- W staging: thread t stages o=t>>2, 16 bf16 at k=(t&3)*16
    const int ow = t >> 2, kq = t & 3;
    const ushort* wsrc = wb + ow * CIN + kq * 16;
    const int wbyte0 = ow * 128 + ((kq * 32) ^ ((ow & 7) << 4));
    const int wbyte1 = ow * 128 + ((kq * 32 + 16) ^ ((ow & 7) << 4));

    f32x4 acc[2][2];
#pragma unroll
    for (int mf = 0; mf < 2; ++mf)
#pragma unroll
        for (int nf = 0; nf < 2; ++nf) acc[mf][nf] = (f32x4){0.f, 0.f, 0.f, 0.f};

    float ldx[2][8];
    uint4 ldw0, ldw1;

    // ---- prologue
#pragma unroll
    for (int j = 0; j < 8; ++j) {
        ldx[0][j] = xb[(kg * 8 + j) * NP];
        ldx[1][j] = xb[(64 + kg * 8 + j) * NP];
    }
    ldw0 = *(const uint4*)(wsrc);
    ldw1 = *(const uint4*)(wsrc + 8);
    {
        bf16x8 v8;
#pragma unroll
        for (int j = 0; j < 8; ++j) v8[j] = (__bf16)ldx[0][j];
        *(bf16x8*)((char*)Xs[0] + xbyte) = v8;
        *(uint4*)((char*)Ws[0] + wbyte0) = ldw0;
        *(uint4*)((char*)Ws[0] + wbyte1) = ldw1;
    }

#pragma unroll
    for (int kc = 0; kc < 8; ++kc) {
        lds_barrier();
        if (kc < 6) {
#pragma unroll
            for (int j = 0; j < 8; ++j)
                ldx[kc & 1][j] = xb[((kc + 2) * 64 + kg * 8 + j) * NP];
        }
        if (kc < 7) {
            ldw0 = *(const uint4*)(wsrc + (kc + 1) * 64);
            ldw1 = *(const uint4*)(wsrc + (kc + 1) * 64 + 8);
        }
#pragma unroll
        for (int ks = 0; ks < 2; ++ks) {
            bf16x8 af[2], bfr[2];
#pragma unroll
            for (int mf = 0; mf < 2; ++mf) {
                int o = wm * 32 + mf * 16 + l15;
                af[mf] = *(const bf16x8*)((const char*)Ws[kc & 1]
                          + o * 128 + ((ks * 64 + lg * 16) ^ ((o & 7) << 4)));
            }
#pragma unroll
            for (int nf = 0; nf < 2; ++nf) {
                int p = wn * 32 + nf * 16 + l15;
                bfr[nf] = *(const bf16x8*)((const char*)Xs[kc & 1]
                           + p * 128 + ((ks * 64 + lg * 16) ^ ((p & 7) << 4)));
            }
#pragma unroll
            for (int mf = 0; mf < 2; ++mf)
#pragma unroll
                for (int nf = 0; nf < 2; ++nf)
                    acc[mf][nf] = __builtin_amdgcn_mfma_f32_16x16x32_bf16(
                        af[mf], bfr[nf], acc[mf][nf], 0, 0, 0);
        }
        if (kc < 7) {
            bf16x8 v8;
#pragma unroll
            for (int j = 0; j < 8; ++j) v8[j] = (__bf16)ldx[(kc + 1) & 1][j];
            *(bf16x8*)((char*)Xs[(kc + 1) & 1] + xbyte) = v8;
            *(uint4*)((char*)Ws[(kc + 1) & 1] + wbyte0) = ldw0;
            *(uint4*)((char*)Ws[(kc + 1) & 1] + wbyte1) = ldw1;
        }
    }

    // ---- epilogue: BN + SiLU, stage h (bf16) in LDS, per-(wn,o) partials
    __syncthreads();                 // all Xs reads done before reuse
    ushort* Hs = (ushort*)Xs;        // [128 o][64 p] ushort = 16KB
#pragma unroll
    for (int mf = 0; mf < 2; ++mf) {
#pragma unroll
        for (int reg = 0; reg < 4; ++reg) {
            int o = wm * 32 + mf * 16 + lg * 4 + reg;
            float sc = bnss[o], sh = bnss[o + COUT];
            float s_ = 0.f, m_ = -1e30f;
#pragma unroll
            for (int nf = 0; nf < 2; ++nf) {
                float d    = acc[mf][nf][reg];
                float hval = d * sc + sh;
                hval       = hval / (1.f + __expf(-hval));
                s_ += hval;
                m_ = fmaxf(m_, hval);
                __bf16 hb = (__bf16)hval;
                Hs[o * 64 + wn * 32 + nf * 16 + l15] = *(ushort*)&hb;
            }
#pragma unroll
            for (int d = 1; d < 16; d <<= 1) {
                s_ += __shfl_xor(s_, d, 64);
                m_ = fmaxf(m_, __shfl_xor(m_, d, 64));
            }
            if (l15 == 0) {
                redS[wn][o] = s_;
                redM[wn][o] = m_;
            }
        }
    }
    __syncthreads();
    if (t < COUT) {
        atomicAdd(&sumh[b * COUT + t], redS[0][t] + redS[1][t]);
        atomicMax(&mxenc[b * COUT + t], fenc(fmaxf(redM[0][t], redM[1][t])));
    }
    // coalesced fp8 h write: thread t -> row t>>2, 16 bytes at (t&3)*16
    {
        int orow = t >> 2, c = t & 3;
        uint4 a  = *(const uint4*)&Hs[orow * 64 + c * 16];
        uint4 b4 = *(const uint4*)&Hs[orow * 64 + c * 16 + 8];
        uint4 o4;
        o4.x = pack4_fp8(a.x, a.y);
        o4.y = pack4_fp8(a.z, a.w);
        o4.z = pack4_fp8(b4.x, b4.y);
        o4.w = pack4_fp8(b4.z, b4.w);
        *(uint4*)&hout[((size_t)b * COUT + orow) * NP + p0 + c * 16] = o4;
    }
}

// ---------------------------------------------------------------------------
// Kernel 2: spatial stats of (h * ca), h in fp8 (LDS decode table).
// Inline ca MLP; block x==0 publishes ca. sbuf[z][b][{sum,max}][p].
// ---------------------------------------------------------------------------
__global__ __launch_bounds__(256) void k_sstat(const uchar* __restrict__ h,
                                               const float* __restrict__ sumh,
                                               const unsigned* __restrict__ mxenc,
                                               const float* __restrict__ w1,
                                               const float* __restrict__ w2,
                                               float* __restrict__ ca,
                                               float* __restrict__ sbuf)
{
    int b = blockIdx.y, z = blockIdx.z;
    int t = threadIdx.x;
    __shared__ float avg[128], mx[128], r1[16], cas[32], tab[256];
    tab[t] = fp8_entry(t);
    if (t < 128) {
        avg[t] = sumh[b * COUT + t] * (1.f / (float)NP);
        mx[t]  = fdec(mxenc[b * COUT + t]);
    }
    __syncthreads();
    if (t < 16) {
        int r = t & 7;
        const float* p = (t < 8) ? avg : mx;
        float s = 0.f;
        for (int c = 0; c < 128; ++c) s += w1[r * 128 + c] * p[c];
        r1[t] = fmaxf(s, 0.f);
    }
    __syncthreads();
    if (t < 32) {
        int o = z * 32 + t;
        float s = 0.f;
#pragma unroll
        for (int r = 0; r < 8; ++r) s += w2[o * 8 + r] * (r1[r] + r1[r + 8]);
        float cv = 1.f / (1.f + __expf(-s));
        cas[t] = cv;
        if (blockIdx.x == 0) ca[b * COUT + o] = cv;
    }
    __syncthreads();

    int idx = blockIdx.x * 256 + t;   // quad index
    if (idx >= NP / 4) return;
    int p = idx * 4;
    const uchar* hb = h + ((size_t)(b * COUT + z * 32)) * NP + p;
    float s0 = 0.f, s1 = 0.f, s2 = 0.f, s3 = 0.f;
    float m0 = -1e30f, m1 = -1e30f, m2 = -1e30f, m3 = -1e30f;
#pragma unroll 4
    for (int c = 0; c < 32; ++c) {
        unsigned u = *(const unsigned*)(hb + (size_t)c * NP);
        float cv = cas[c];
        float v0 = tab[u & 255] * cv;
        float v1 = tab[(u >> 8) & 255] * cv;
        float v2 = tab[(u >> 16) & 255] * cv;
        float v3 = tab[u >> 24] * cv;
        s0 += v0; s1 += v1; s2 += v2; s3 += v3;
        m0 = fmaxf(m0, v0); m1 = fmaxf(m1, v1);
        m2 = fmaxf(m2, v2); m3 = fmaxf(m3, v3);
    }
    float* sb = sbuf + ((size_t)(z * NB + b) * 2) * NP;
    *(float4*)&sb[p]      = make_float4(s0, s1, s2, s3);
    *(float4*)&sb[NP + p] = make_float4(m0, m1, m2, m3);
}

// ---------------------------------------------------------------------------
// Kernel 3: combine quarters, 7x7 conv (pad 3) + sigmoid -> sigsa[32,3136]
// ---------------------------------------------------------------------------
__global__ __launch_bounds__(256) void k_conv(const float* __restrict__ sbuf,
                                              const float* __restrict__ saw,
                                              float* __restrict__ sigsa)
{
    int band = blockIdx.x, b = blockIdx.y;
    int y0 = band * 7;
    int t = threadIdx.x;
    __shared__ float s[2][13 * WIMG];
    __shared__ float w[98];
    if (t < 98) w[t] = saw[t];
    for (int i = t; i < 13 * WIMG; i += 256) {
        int yy = y0 - 3 + i / WIMG;
        float vs = 0.f, vm = 0.f;
        if (yy >= 0 && yy < WIMG) {
            int p = yy * WIMG + (i % WIMG);
            float ssum = 0.f, smax = -1e30f;
#pragma unroll
            for (int z = 0; z < 4; ++z) {
                const float* sb = sbuf + ((size_t)(z * NB + b) * 2) * NP;
                ssum += sb[p];
                smax = fmaxf(smax, sb[NP + p]);
            }
            vs = ssum * (1.f / (float)COUT);
            vm = smax;
        }
        s[0][i] = vs;
        s[1][i] = vm;
    }
    __syncthreads();
    for (int i = t; i < 7 * WIMG; i += 256) {
        int ly = i / WIMG, px = i % WIMG;
        float a = 0.f;
#pragma unroll
        for (int ch = 0; ch < 2; ++ch) {
#pragma unroll
            for (int dy = 0; dy < 7; ++dy) {
                int li = (ly + dy) * WIMG;
                for (int dx = 0; dx < 7; ++dx) {
                    int xx = px + dx - 3;
                    if (xx < 0 || xx >= WIMG) continue;
                    a += s[ch][li + xx] * w[ch * 49 + dy * 7 + dx];
                }
            }
        }
        sigsa[b * NP + (y0 + ly) * WIMG + px] = 1.f / (1.f + __expf(-a));
    }
}

// ---------------------------------------------------------------------------
// Kernel 4: t = sum_p h * sigsa ; y = (sum_h + ca*t)/P.  One block per (b,o).
// ---------------------------------------------------------------------------
__global__ __launch_bounds__(256) void k_wsum(const uchar* __restrict__ h,
                                              const float* __restrict__ sigsa,
                                              const float* __restrict__ sumh,
                                              const float* __restrict__ ca,
                                              float* __restrict__ y)
{
    int bo = blockIdx.x;          // b*128+o
    int b = bo >> 7;
    int t = threadIdx.x;
    __shared__ float tab[256];
    __shared__ float part[4];
    tab[t] = fp8_entry(t);
    __syncthreads();
    const uchar* hr = h + (size_t)bo * NP;
    const float* sg  = sigsa + (size_t)b * NP;
    float s = 0.f;
#pragma unroll
    for (int i = 0; i < 3; ++i) {
        int q = i * 256 + t;
        unsigned u = *(const unsigned*)(hr + q * 4);
        float4 g = *(const float4*)(sg + q * 4);
        s += tab[u & 255] * g.x + tab[(u >> 8) & 255] * g.y
           + tab[(u >> 16) & 255] * g.z + tab[u >> 24] * g.w;
    }
    if (t < 16) {
        int q = 768 + t;
        unsigned u = *(const unsigned*)(hr + q * 4);
        float4 g = *(const float4*)(sg + q * 4);
        s += tab[u & 255] * g.x + tab[(u >> 8) & 255] * g.y
           + tab[(u >> 16) & 255] * g.z + tab[u >> 24] * g.w;
    }
#pragma unroll
    for (int d = 1; d < 64; d <<= 1) s += __shfl_xor(s, d, 64);
    if ((t & 63) == 0) part[t >> 6] = s;
    __syncthreads();
    if (t == 0) {
        float tt = part[0] + part[1] + part[2] + part[3];
        y[bo] = (sumh[bo] + ca[bo] * tt) * (1.f / (float)NP);
    }
}

// ---------------------------------------------------------------------------
// Kernel 5: LayerNorm over channels -> out[32,128]
// ---------------------------------------------------------------------------
__global__ void k_ln(const float* __restrict__ y, const float* __restrict__ g,
                     const float* __restrict__ bta, float* __restrict__ out)
{
    int b = blockIdx.x, t = threadIdx.x;  // 128 threads
    __shared__ float pr[2], pr2[2];
    float v = y[b * COUT + t];
    float s = v;
#pragma unroll
    for (int d = 1; d < 64; d <<= 1) s += __shfl_xor(s, d, 64);
    if ((t & 63) == 0) pr[t >> 6] = s;
    __syncthreads();
    float mu = (pr[0] + pr[1]) * (1.f / (float)COUT);
    float dv = v - mu;
    float q = dv * dv;
#pragma unroll
    for (int d = 1; d < 64; d <<= 1) q += __shfl_xor(q, d, 64);
    if ((t & 63) == 0) pr2[t >> 6] = q;
    __syncthreads();
    float var = (pr2[0] + pr2[1]) * (1.f / (float)COUT);
    out[b * COUT + t] = dv * rsqrtf(var + 1e-5f) * g[t] + bta[t];
}

// ---------------------------------------------------------------------------
extern "C" void kernel_launch(void* const* d_in, const int* in_sizes, int n_in,
                              void* d_out, int out_size, void* d_ws, size_t ws_size,
                              hipStream_t stream)
{
    const float* x     = (const float*)d_in[0];
    const float* wp    = (const float*)d_in[1];
    const float* bn_g  = (const float*)d_in[2];
    const float* bn_b  = (const float*)d_in[3];
    const float* bn_m  = (const float*)d_in[4];
    const float* bn_v  = (const float*)d_in[5];
    const float* ca_w1 = (const float*)d_in[6];
    const float* ca_w2 = (const float*)d_in[7];
    const float* sa_w  = (const float*)d_in[8];
    const float* ln_g  = (const float*)d_in[9];
    const float* ln_b  = (const float*)d_in[10];
    float* out = (float*)d_out;

    char* ws = (char*)d_ws;
    size_t off = 0;
    uchar*    hbuf  = (uchar*)(ws + off);    off += (size_t)NB * COUT * NP;      // 12.8 MB
    float*    sumh  = (float*)(ws + off);    off += NB * COUT * 4;               // 16 KB
    unsigned* mxenc = (unsigned*)(ws + off); off += NB * COUT * 4;               // 16 KB
    float*    ca    = (float*)(ws + off);    off += NB * COUT * 4;               // 16 KB
    float*    sbuf  = (float*)(ws + off);    off += (size_t)4 * NB * 2 * NP * 4; // 3.2 MB
    float*    sigsa = (float*)(ws + off);    off += (size_t)NB * NP * 4;         // 0.4 MB
    float*    ybuf  = (float*)(ws + off);    off += NB * COUT * 4;
    ushort*   wb16  = (ushort*)(ws + off);   off += (size_t)COUT * CIN * 2;      // 128 KB

    k_wcvt<<<64, 256, 0, stream>>>(wp, wb16, (unsigned*)sumh);
    k_main<<<NB * 49, 512, 0, stream>>>(x, wb16, bn_g, bn_b, bn_m, bn_v, hbuf, sumh, mxenc);
    k_sstat<<<dim3(4, NB, 4), 256, 0, stream>>>(hbuf, sumh, mxenc, ca_w1, ca_w2, ca, sbuf);
    k_conv<<<dim3(8, NB), 256, 0, stream>>>(sbuf, sa_w, sigsa);
    k_wsum<<<NB * COUT, 256, 0, stream>>>(hbuf, sigsa, sumh, ca, ybuf);
    k_ln<<<NB, 128, 0, stream>>>(ybuf, ln_g, ln_b, out);
}